// Round 7
// baseline (201.201 us; speedup 1.0000x reference)
//
#include <hip/hip_runtime.h>

// QuantumLayer: AmplitudeEmbedding(normalize) + per-wire RX(w_i) + <Z_i>.
// Closed form: out[b][i] = cos(w_i) * (1 - 2 * S_i / SS)
//   SS  = sum_k x[b][k]^2            (after NaN->0 scrub)
//   S_i = sum_{k : bit_(3-i)(k)==1} x[b][k]^2
// (U = tensor RX(w_i); U^T Z_i U = cos Z_i + sin Y_i; <Y_i> = 0 on real state.)
//
// R4 note: the harness's 512 MiB d_ws 0xAA fill each iteration sweeps the
// 256 MiB L3, so x is never cache-resident: kernel is HBM-bound both ways
// (floor ~25 us @ 6.8 TB/s). This round: one SAMPLE per thread -> zero
// cross-lane ops (the old 7 ds_bpermute/iter chain), 4 independent dwordx4
// loads per sample, one coalesced dwordx4 store of all 4 outputs.
// (R5/R6: resubmitted unchanged — benches were acquisition timeouts.)

constexpr int BLOCK = 256;
constexpr int MAX_BLOCKS = 2048;   // 256 CU x 8 blocks/CU; grid-stride the rest

typedef float fvec4 __attribute__((ext_vector_type(4)));

__device__ __forceinline__ void squares(fvec4 v, float& q, float& t2, float& t3) {
    // NaN scrub then square; within a quarter [e0 e1 e2 e3]:
    //   q = all, t2 = e2^2+e3^2 (bit1 set), t3 = e1^2+e3^2 (bit0 set)
    float a = (v.x != v.x) ? 0.0f : v.x;
    float b = (v.y != v.y) ? 0.0f : v.y;
    float c = (v.z != v.z) ? 0.0f : v.z;
    float d = (v.w != v.w) ? 0.0f : v.w;
    float p0 = a * a, p1 = b * b, p2 = c * c, p3 = d * d;
    t2 = p2 + p3;
    t3 = p1 + p3;
    q  = (p0 + p1) + t2;
}

__global__ __launch_bounds__(BLOCK) void quantum_z_kernel(
    const float* __restrict__ x,
    const float* __restrict__ w,
    float* __restrict__ out,
    int n_samples)
{
    const float cw0 = cosf(w[0]), cw1 = cosf(w[1]);
    const float cw2 = cosf(w[2]), cw3 = cosf(w[3]);

    const int stride = gridDim.x * BLOCK;
    for (int s = blockIdx.x * BLOCK + threadIdx.x; s < n_samples; s += stride) {
        const fvec4* xp = reinterpret_cast<const fvec4*>(x) + (size_t)s * 4;
        // 4 independent 16B loads (64B/thread; wave covers 4KiB contiguous)
        fvec4 v0 = __builtin_nontemporal_load(xp + 0);
        fvec4 v1 = __builtin_nontemporal_load(xp + 1);
        fvec4 v2 = __builtin_nontemporal_load(xp + 2);
        fvec4 v3 = __builtin_nontemporal_load(xp + 3);

        float q0, t20, t30, q1, t21, t31, q2, t22, t32, q3, t23, t33;
        squares(v0, q0, t20, t30);
        squares(v1, q1, t21, t31);
        squares(v2, q2, t22, t32);
        squares(v3, q3, t23, t33);

        // element k = quarter*4 + jj: bit3 = quarter>>1, bit2 = quarter&1,
        // bit1 = jj>>1, bit0 = jj&1
        float SS = (q0 + q1) + (q2 + q3);
        float S0 = q2 + q3;                         // wire 0 (bit3)
        float S1 = q1 + q3;                         // wire 1 (bit2)
        float S2 = (t20 + t21) + (t22 + t23);       // wire 2 (bit1)
        float S3 = (t30 + t31) + (t32 + t33);       // wire 3 (bit0)

        float inv2 = -2.0f / SS;                    // one divide per sample
        fvec4 o;
        o.x = cw0 * __builtin_fmaf(S0, inv2, 1.0f);
        o.y = cw1 * __builtin_fmaf(S1, inv2, 1.0f);
        o.z = cw2 * __builtin_fmaf(S2, inv2, 1.0f);
        o.w = cw3 * __builtin_fmaf(S3, inv2, 1.0f);

        // one coalesced 16B store of all 4 outputs
        __builtin_nontemporal_store(o, reinterpret_cast<fvec4*>(out) + s);
    }
}

extern "C" void kernel_launch(void* const* d_in, const int* in_sizes, int n_in,
                              void* d_out, int out_size, void* d_ws, size_t ws_size,
                              hipStream_t stream) {
    const float* x = (const float*)d_in[0];   // [BATCH, 16] f32
    const float* w = (const float*)d_in[1];   // [4] f32
    float* out = (float*)d_out;               // [BATCH, 4] f32

    int n_samples = in_sizes[0] / 16;         // one thread per 16-amp sample
    int grid = (n_samples + BLOCK - 1) / BLOCK;
    if (grid > MAX_BLOCKS) grid = MAX_BLOCKS;
    hipLaunchKernelGGL(quantum_z_kernel, dim3(grid), dim3(BLOCK), 0, stream,
                       x, w, out, n_samples);
}

// Round 9
// 196.278 us; speedup vs baseline: 1.0251x; 1.0251x over previous
//
#include <hip/hip_runtime.h>

// QuantumLayer: AmplitudeEmbedding(normalize) + per-wire RX(w_i) + <Z_i>.
// Closed form: out[b][i] = cos(w_i) * (1 - 2 * S_i / SS)
//   SS  = sum_k x[b][k]^2            (after NaN->0 scrub)
//   S_i = sum_{k : bit_(3-i)(k)==1} x[b][k]^2
// (U = tensor RX(w_i); U^T Z_i U = cos Z_i + sin Y_i; <Y_i> = 0 on real state.)
//
// R8: R3's perfectly-coalesced layout (4 lanes per sample, one float4 each,
// per-instruction contiguous 16B/lane) + quad reduction via DPP quad_perm
// (VALU pipe, no ds_bpermute LDS-pipe chain) + EXACT grid (one work item
// per thread, 8.4M threads, no grid-stride loop) for max TLP.
// (R9: resubmitted unchanged — R8 bench was an acquisition timeout.)

constexpr int BLOCK = 256;

typedef float fvec4 __attribute__((ext_vector_type(4)));

// quad_perm DPP cross-lane read within each 4-lane quad (VALU-rate).
// CTRL: [1,0,3,2] = 0xB1 (xor 1), [2,3,0,1] = 0x4E (xor 2).
template <int CTRL>
__device__ __forceinline__ float dpp_qperm(float x) {
    int r = __builtin_amdgcn_update_dpp(
        0, __builtin_bit_cast(int, x), CTRL, 0xf, 0xf, true);
    return __builtin_bit_cast(float, r);
}
#define DPP_XOR1 0xB1
#define DPP_XOR2 0x4E

__global__ __launch_bounds__(BLOCK) void quantum_z_kernel(
    const float* __restrict__ x,
    const float* __restrict__ w,
    float* __restrict__ out,
    int n_vec4)
{
    int gid = blockIdx.x * BLOCK + threadIdx.x;
    if (gid >= n_vec4) return;
    const int j = gid & 3;               // quarter index within the sample
    const float cw = cosf(w[j]);

    // one contiguous float4 per lane: wave covers 1 KiB per instruction
    fvec4 v = __builtin_nontemporal_load(reinterpret_cast<const fvec4*>(x) + gid);

    // NaN scrub (reference semantics; no-op on real data)
    float a = (v.x != v.x) ? 0.0f : v.x;
    float b = (v.y != v.y) ? 0.0f : v.y;
    float c = (v.z != v.z) ? 0.0f : v.z;
    float d = (v.w != v.w) ? 0.0f : v.w;

    float p0 = a * a, p1 = b * b, p2 = c * c, p3 = d * d;
    float t2 = p2 + p3;                  // bit1-set elems of this quarter
    float t3 = p1 + p3;                  // bit0-set elems of this quarter
    float q  = (p0 + p1) + t2;           // this quarter's sum of squares

    // quad reduction, element k = j*4 + jj:
    //   bit3 = j>>1, bit2 = j&1, bit1 = jj>>1, bit0 = jj&1
    float r1q  = dpp_qperm<DPP_XOR1>(q);
    float pair = q + r1q;                          // {q0+q1, q2+q3}
    float oddq = (j & 1) ? q : r1q;                // q of odd lane in pair
    float r2p  = dpp_qperm<DPP_XOR2>(pair);
    float SS   = pair + r2p;                       // full sum of squares
    float S0   = (j & 2) ? pair : r2p;             // q2+q3   (wire 0, bit3)
    float S1   = oddq + dpp_qperm<DPP_XOR2>(oddq); // q1+q3   (wire 1, bit2)
    float S2   = t2 + dpp_qperm<DPP_XOR1>(t2);     // wire 2  (bit1)
    S2 += dpp_qperm<DPP_XOR2>(S2);
    float S3   = t3 + dpp_qperm<DPP_XOR1>(t3);     // wire 3  (bit0)
    S3 += dpp_qperm<DPP_XOR2>(S3);

    // lane j emits output component j (contiguous dword store)
    float Sj = (j & 2) ? ((j & 1) ? S3 : S2) : ((j & 1) ? S1 : S0);
    float z  = cw * __builtin_fmaf(Sj, -2.0f / SS, 1.0f);
    __builtin_nontemporal_store(z, out + gid);
}

extern "C" void kernel_launch(void* const* d_in, const int* in_sizes, int n_in,
                              void* d_out, int out_size, void* d_ws, size_t ws_size,
                              hipStream_t stream) {
    const float* x = (const float*)d_in[0];   // [BATCH, 16] f32
    const float* w = (const float*)d_in[1];   // [4] f32
    float* out = (float*)d_out;               // [BATCH, 4] f32

    int n_vec4 = in_sizes[0] / 4;             // one thread per float4 (exact grid)
    int grid = (n_vec4 + BLOCK - 1) / BLOCK;  // 32768 blocks — max TLP
    hipLaunchKernelGGL(quantum_z_kernel, dim3(grid), dim3(BLOCK), 0, stream,
                       x, w, out, n_vec4);
}